// Round 7
// baseline (234.898 us; speedup 1.0000x reference)
//
#include <hip/hip_runtime.h>
#include <hip/hip_bf16.h>

#define B_SZ 4
#define T_SEQ 1024
#define DM 128
#define ED_ 256
#define NS 64
#define CLEN 64

// workspace layout (float elements). Total = 6,389,760 floats = 25.6 MB.
// Aliasing: S overwrites xsr (dead after k4b); sd overwrites Wc (dead after k4b).
#define OFF_Z      0u         /* 524288  f32  z (residual, read by K6)            */
#define OFF_BM     524288u    /* 262144  f32  B matrix                            */
#define OFF_CM     786432u    /* 262144  f32  C matrix                            */
#define OFF_XSR    1048576u   /* 1048576 f32  conv input (k2f->k4b); later S      */
#define OFF_ZG     2097152u   /* 1048576 f32  gate (read by K6)                   */
#define OFF_XS     3145728u   /* 1048576 f32  conv+silu output (k4b->k5a,k5c,k6)  */
#define OFF_WC     4194304u   /* 98304   f32  combined weight (k2f->k4b); later sd*/
#define OFF_YR     4292608u   /* 1048576 f32  raw scan output (k5c -> k6)         */
#define OFF_DELTA  5341184u   /* 1048576 f32  softplus delta (k4b -> k5a,k5c)     */
#define OFF_S      (OFF_XSR)
#define OFF_SD     (OFF_WC)

__device__ __forceinline__ float sigmoidf_(float x){ return 1.f/(1.f+__expf(-x)); }

// DPP reduce step: 0x111/0x112/0x114/0x118 = row_shr 1/2/4/8, 0x142/0x143 =
// row_bcast15/31. After all six, lane 63 holds the wave sum.
#define DPPSTEP(p, ctl) p += __int_as_float(__builtin_amdgcn_update_dpp(0, __float_as_int(p), ctl, 0xf, 0xf, false))

// Shared (b,e,c) mapping for k5a/k5c. 4096 blocks, 4 waves each.
// XCD-aware: block i -> XCD i%8; each XCD owns 2 of the 16 delta-line groups
// (16 consecutive e = one 64B line), so delta/xs lines stay in one XCD's L2.
__device__ __forceinline__ void scan_map(int i, int w, int& b, int& c, int& e){
  int x = i & 7;
  int j = i >> 3;
  int lg = x*2 + (j & 1);
  int j2 = j >> 1;           // 0..255
  b = j2 & 3;
  c = (j2 >> 2) & 15;
  int q = j2 >> 6;           // 0..3
  e = lg*16 + q*4 + w;
}

// K2f: blocks 0..511: fused [z = zseq+aux@auxW.T+auxb ; zn=RMSNorm(z)*rms_w] -> LDS,
//      then xz = zn @ in_proj_W.T -> xsr | zg. 8 rows/block.
//      blocks 512..895: build combined weight Wc.
__global__ __launch_bounds__(256) void k2_fused(const float* zseq, const float* aux, const float* auxW,
                                                const float* auxb, const float* rmsw, const float* W,
                                                const float* xprojW, const float* dtW,
                                                float* z, float* xsr, float* zg, float* Wc){
  if (blockIdx.x >= 512){
    int r = blockIdx.x - 512; int k = threadIdx.x;
    float v;
    if (r < 256){
      v = 0.f;
      #pragma unroll
      for (int j=0;j<8;j++) v += dtW[r*8+j] * xprojW[j*256+k];
    } else {
      v = xprojW[(8 + r-256)*256 + k];
    }
    Wc[r*256+k] = v;
    return;
  }
  __shared__ float at[128][8];
  int bt0 = blockIdx.x*8; int tid = threadIdx.x;
  {
    int r = tid>>5, l = tid&31;
    int bt = bt0 + r;
    float a0 = aux[bt*3+0], a1 = aux[bt*3+1], a2 = aux[bt*3+2];
    float zv[4]; float ssq = 0.f;
    #pragma unroll
    for (int j=0;j<4;j++){
      int d = l + 32*j;
      float v = zseq[bt*DM+d] + a0*auxW[d*3+0] + a1*auxW[d*3+1] + a2*auxW[d*3+2] + auxb[d];
      zv[j] = v; ssq += v*v;
    }
    #pragma unroll
    for (int m=16;m>=1;m>>=1) ssq += __shfl_xor(ssq, m);
    float rinv = rsqrtf(ssq*(1.f/DM) + 1e-5f);
    #pragma unroll
    for (int j=0;j<4;j++){
      int d = l + 32*j;
      z[bt*DM+d] = zv[j];
      at[d][r] = zv[j]*rinv*rmsw[d];
    }
  }
  __syncthreads();
  float acc0[8], acc1[8];
  #pragma unroll
  for (int r=0;r<8;r++){ acc0[r]=0.f; acc1[r]=0.f; }
  int c0 = tid, c1 = tid+256;
  for (int k=0;k<128;k+=4){
    float4 w0v = *(const float4*)(W + c0*128 + k);
    float4 w1v = *(const float4*)(W + c1*128 + k);
    float w0[4] = {w0v.x, w0v.y, w0v.z, w0v.w};
    float w1[4] = {w1v.x, w1v.y, w1v.z, w1v.w};
    #pragma unroll
    for (int kk=0;kk<4;kk++){
      float a[8];
      *(float4*)&a[0] = *(const float4*)&at[k+kk][0];
      *(float4*)&a[4] = *(const float4*)&at[k+kk][4];
      #pragma unroll
      for (int r=0;r<8;r++){ acc0[r] = fmaf(a[r], w0[kk], acc0[r]); acc1[r] = fmaf(a[r], w1[kk], acc1[r]); }
    }
  }
  #pragma unroll
  for (int r=0;r<8;r++){
    int bt = bt0+r;
    xsr[bt*ED_ + c0] = acc0[r];
    zg [bt*ED_ + c0] = acc1[r];
  }
}

// K4b: staging computes conv(k=4)+bias+SiLU from xsr (writes xs), then
// [delta_pre | B | C] = xs @ Wc.T ; delta = softplus(delta_pre + dt_b)
__global__ __launch_bounds__(384) void k4b_xproj(const float* xsr, const float* convW, const float* convb,
                                                 const float* Wc, const float* dtb,
                                                 float* xs, float* delta, float* Bm, float* Cm){
  __shared__ float at[256][8];
  int bt0 = blockIdx.x*8; int tid = threadIdx.x;
  for (int i=tid;i<2048;i+=384){
    int r=i>>8,k=i&255; int bt=bt0+r; int t = bt & (T_SEQ-1);
    float4 wv = *(const float4*)(convW + k*4);
    float s = convb[k];
    if (t>=3) s += xsr[(bt-3)*ED_+k]*wv.x;
    if (t>=2) s += xsr[(bt-2)*ED_+k]*wv.y;
    if (t>=1) s += xsr[(bt-1)*ED_+k]*wv.z;
    s += xsr[bt*ED_+k]*wv.w;
    float v = s * sigmoidf_(s);
    at[k][r] = v;
    xs[bt*ED_+k] = v;
  }
  __syncthreads();
  float acc[8];
  #pragma unroll
  for (int r=0;r<8;r++) acc[r]=0.f;
  int c = tid;
  for (int k=0;k<256;k+=4){
    float4 wv = *(const float4*)(Wc + c*256 + k);
    float w[4] = {wv.x, wv.y, wv.z, wv.w};
    #pragma unroll
    for (int kk=0;kk<4;kk++){
      float a[8];
      *(float4*)&a[0] = *(const float4*)&at[k+kk][0];
      *(float4*)&a[4] = *(const float4*)&at[k+kk][4];
      #pragma unroll
      for (int r=0;r<8;r++) acc[r] = fmaf(a[r], w[kk], acc[r]);
    }
  }
  if (c < 256){
    float bc = dtb[c];
    #pragma unroll
    for (int r=0;r<8;r++){
      float x = acc[r] + bc;
      delta[(bt0+r)*ED_ + c] = (x > 20.f) ? x : log1pf(__expf(x));
    }
  } else if (c < 320){
    #pragma unroll
    for (int r=0;r<8;r++) Bm[(bt0+r)*NS + (c-256)] = acc[r];
  } else {
    #pragma unroll
    for (int r=0;r<8;r++) Cm[(bt0+r)*NS + (c-320)] = acc[r];
  }
}

// K5a: per-chunk local scan (seed 0). Wave (b,e,c) over 64 t. Stores local end
// state S[g*64+n] and chunk delta-sum sd[g] (lane-uniform, lane 0 writes).
// 16384 waves -> full occupancy; latency hidden by TLP.
__global__ __launch_bounds__(256) void k5a_chunk(const float* delta, const float* xs, const float* Bm,
                                                  const float* Alog, float* S, float* sd_out){
  int w = threadIdx.x >> 6, n = threadIdx.x & 63;
  int b, c, e; scan_map(blockIdx.x, w, b, c, e);
  float A = -__expf(Alog[e*NS+n]);
  int base = b*T_SEQ + c*CLEN;
  const float* pd = delta + (size_t)base*ED_ + e;
  const float* px = xs    + (size_t)base*ED_ + e;
  const float* pb = Bm    + (size_t)base*NS  + n;
  float h = 0.f, sd = 0.f;
  for (int t=0; t<CLEN; t+=8){
    float dl[8], xx[8], bb[8];
    #pragma unroll
    for (int j=0;j<8;j++){ int s=t+j; dl[j]=pd[s*ED_]; xx[j]=px[s*ED_]; bb[j]=pb[s*NS]; }
    #pragma unroll
    for (int j=0;j<8;j++){
      float a = __expf(dl[j]*A);
      h = fmaf(a, h, dl[j]*xx[j]*bb[j]);
      sd += dl[j];
    }
  }
  int g = (b*256 + e)*16 + c;
  S[g*NS+n] = h;
  if (n==0) sd_out[g] = sd;
}

// K5c: prologue folds chunks 0..c-1 into seed h (P recomputed as exp(sd*A));
// then local scan with DPP C-dot, storing raw p[t] from lane 63.
__global__ __launch_bounds__(256) void k5c_scan(const float* delta, const float* xs, const float* Bm,
                                                 const float* Cm, const float* Alog,
                                                 const float* S, const float* sd_in, float* yraw){
  int w = threadIdx.x >> 6, n = threadIdx.x & 63;
  int b, c, e; scan_map(blockIdx.x, w, b, c, e);
  float A = -__expf(Alog[e*NS+n]);
  int gbase = (b*256 + e)*16;
  float h = 0.f;
  for (int cc=0; cc<c; ++cc){            // c is block-uniform -> no divergence
    float p = __expf(sd_in[gbase+cc]*A);
    h = fmaf(p, h, S[(gbase+cc)*NS+n]);
  }
  int base = b*T_SEQ + c*CLEN;
  const float* pd = delta + (size_t)base*ED_ + e;
  const float* px = xs    + (size_t)base*ED_ + e;
  const float* pb = Bm    + (size_t)base*NS  + n;
  const float* pc = Cm    + (size_t)base*NS  + n;
  float*       py = yraw  + (size_t)base*ED_ + e;
  bool last = (n==63);
  for (int t=0; t<CLEN; t+=8){
    float dl[8], xx[8], bb[8], cc8[8], pp[8];
    #pragma unroll
    for (int j=0;j<8;j++){ int s=t+j; dl[j]=pd[s*ED_]; xx[j]=px[s*ED_]; bb[j]=pb[s*NS]; cc8[j]=pc[s*NS]; }
    #pragma unroll
    for (int j=0;j<8;j++){
      float a = __expf(dl[j]*A);
      h = fmaf(a, h, dl[j]*xx[j]*bb[j]);
      pp[j] = h*cc8[j];
    }
    #pragma unroll
    for (int j=0;j<8;j++) DPPSTEP(pp[j], 0x111);
    #pragma unroll
    for (int j=0;j<8;j++) DPPSTEP(pp[j], 0x112);
    #pragma unroll
    for (int j=0;j<8;j++) DPPSTEP(pp[j], 0x114);
    #pragma unroll
    for (int j=0;j<8;j++) DPPSTEP(pp[j], 0x118);
    #pragma unroll
    for (int j=0;j<8;j++) DPPSTEP(pp[j], 0x142);
    #pragma unroll
    for (int j=0;j<8;j++) DPPSTEP(pp[j], 0x143);
    if (last){
      #pragma unroll
      for (int j=0;j<8;j++) py[(t+j)*ED_] = pp[j];
    }
  }
}

// K6: y = (yraw + D*xs)*silu(zg);  out = LayerNorm(y @ out_proj_W.T + 2*z)*ln_w + ln_b
__global__ __launch_bounds__(256) void k6_out(const float* yraw, const float* xs, const float* zg,
                                               const float* Dp, const float* W, const float* z,
                                               const float* lnw, const float* lnb, float* out){
  __shared__ float yt[256][8];
  __shared__ float psum[4][4], psq[4][4];
  int bt0 = blockIdx.x*8; int tid = threadIdx.x;
  int d = tid & 127, gdx = tid>>7;
  for (int i=tid;i<2048;i+=256){
    int r=i>>8,k=i&255; int bt=bt0+r;
    float zgv = zg[bt*ED_ + k];
    float yv  = yraw[bt*ED_ + k] + Dp[k]*xs[bt*ED_ + k];
    yt[k][r] = yv * zgv * sigmoidf_(zgv);
  }
  __syncthreads();
  float acc[4] = {0.f,0.f,0.f,0.f};
  for (int k=0;k<256;k+=4){
    float4 wv = *(const float4*)(W + d*256 + k);
    float w[4] = {wv.x, wv.y, wv.z, wv.w};
    #pragma unroll
    for (int kk=0;kk<4;kk++){
      float4 q = *(const float4*)&yt[k+kk][gdx*4];
      acc[0] = fmaf(q.x, w[kk], acc[0]);
      acc[1] = fmaf(q.y, w[kk], acc[1]);
      acc[2] = fmaf(q.z, w[kk], acc[2]);
      acc[3] = fmaf(q.w, w[kk], acc[3]);
    }
  }
  float val[4];
  #pragma unroll
  for (int j=0;j<4;j++){
    int bt = bt0 + gdx*4 + j;
    val[j] = acc[j] + 2.f*z[bt*DM + d];
  }
  int w_id = tid>>6;
  #pragma unroll
  for (int j=0;j<4;j++){
    float s = val[j], q = val[j]*val[j];
    #pragma unroll
    for (int off=32; off>=1; off>>=1){ s += __shfl_down(s, off); q += __shfl_down(q, off); }
    if ((tid&63)==0){ psum[w_id][j]=s; psq[w_id][j]=q; }
  }
  __syncthreads();
  float lw = lnw[d], lb = lnb[d];
  #pragma unroll
  for (int j=0;j<4;j++){
    int bt = bt0 + gdx*4 + j;
    float sum = psum[gdx*2][j] + psum[gdx*2+1][j];
    float sq  = psq [gdx*2][j] + psq [gdx*2+1][j];
    float mu  = sum*(1.f/DM);
    float var = sq*(1.f/DM) - mu*mu;
    float inv = rsqrtf(var + 1e-5f);
    out[bt*DM + d] = (val[j]-mu)*inv*lw + lb;
  }
}

extern "C" void kernel_launch(void* const* d_in, const int* in_sizes, int n_in,
                              void* d_out, int out_size, void* d_ws, size_t ws_size,
                              hipStream_t stream){
  const float* zseq = (const float*)d_in[0];
  const float* aux  = (const float*)d_in[1];
  const float* auxW = (const float*)d_in[2];
  const float* auxb = (const float*)d_in[3];
  const float* lnw  = (const float*)d_in[4];
  const float* lnb  = (const float*)d_in[5];
  const float* rmsw = (const float*)d_in[6];
  const float* inW  = (const float*)d_in[7];
  const float* convW= (const float*)d_in[8];
  const float* convb= (const float*)d_in[9];
  const float* xpW  = (const float*)d_in[10];
  const float* dtW  = (const float*)d_in[11];
  const float* dtb  = (const float*)d_in[12];
  const float* Alog = (const float*)d_in[13];
  const float* Dp   = (const float*)d_in[14];
  const float* outW = (const float*)d_in[15];
  float* out = (float*)d_out;
  float* ws = (float*)d_ws;

  float* z   = ws+OFF_Z;
  float* Bm  = ws+OFF_BM;   float* Cm = ws+OFF_CM;
  float* xsr = ws+OFF_XSR;  float* zg = ws+OFF_ZG;   float* xs = ws+OFF_XS;
  float* Wc  = ws+OFF_WC;
  float* yr  = ws+OFF_YR;   float* dl = ws+OFF_DELTA;
  float* S   = ws+OFF_S;    float* sd = ws+OFF_SD;

  k2_fused <<<896,256,0,stream>>>(zseq,aux,auxW,auxb,rmsw,inW,xpW,dtW,z,xsr,zg,Wc);
  k4b_xproj<<<512,384,0,stream>>>(xsr,convW,convb,Wc,dtb,xs,dl,Bm,Cm);
  k5a_chunk<<<4096,256,0,stream>>>(dl,xs,Bm,Alog,S,sd);
  k5c_scan <<<4096,256,0,stream>>>(dl,xs,Bm,Cm,Alog,S,sd,yr);
  k6_out   <<<512,256,0,stream>>>(yr,xs,zg,Dp,outW,z,lnw,lnb,out);
}